// Round 3
// baseline (828.687 us; speedup 1.0000x reference)
//
#include <hip/hip_runtime.h>
#include <stdint.h>

#define BATCH 4
#define S_LEN 4096
#define D_DIM 1024
static constexpr float ATTN_SCALE = 0.03125f; // 1/sqrt(1024)

typedef __attribute__((ext_vector_type(8))) short short8_t;
typedef __attribute__((ext_vector_type(4))) float f32x4;

// ---------- bf16 helpers ----------
__device__ __forceinline__ unsigned short f2b(float f) {
    union { float f; uint32_t i; } x; x.f = f;
    uint32_t r = x.i + 0x7FFF + ((x.i >> 16) & 1);
    return (unsigned short)(r >> 16);
}
__device__ __forceinline__ float b2f(unsigned short u) {
    union { uint32_t i; float f; } x; x.i = ((uint32_t)u) << 16;
    return x.f;
}

// ---------- async global->LDS 16B ----------
__device__ __forceinline__ void gl_lds16(const unsigned short* g, unsigned short* l) {
    __builtin_amdgcn_global_load_lds(
        (const __attribute__((address_space(1))) uint32_t*)(const void*)g,
        (__attribute__((address_space(3))) uint32_t*)(void*)l,
        16, 0, 0);
}

// ---------- one prep kernel: all casts + bias pack ----------
__device__ __forceinline__ void cast8(const float* in, unsigned short* out, int i) {
    float4 a = *(const float4*)(in + i);
    float4 b = *(const float4*)(in + i + 4);
    short8_t o;
    o[0] = (short)f2b(a.x); o[1] = (short)f2b(a.y);
    o[2] = (short)f2b(a.z); o[3] = (short)f2b(a.w);
    o[4] = (short)f2b(b.x); o[5] = (short)f2b(b.y);
    o[6] = (short)f2b(b.z); o[7] = (short)f2b(b.w);
    *(short8_t*)(out + i) = o;
}

__global__ __launch_bounds__(256) void prep(
    const float* __restrict__ x,
    const float* __restrict__ Wq, const float* __restrict__ Wk,
    const float* __restrict__ Wv, const float* __restrict__ Wo,
    const float* __restrict__ bq, const float* __restrict__ bk,
    const float* __restrict__ bv,
    unsigned short* __restrict__ xb, unsigned short* __restrict__ Wqkvb,
    unsigned short* __restrict__ Wob, float* __restrict__ bqkv) {
    const int nX8 = (BATCH * S_LEN * D_DIM) / 8; // 2097152
    const int nW8 = (D_DIM * D_DIM) / 8;         // 131072
    int gid = blockIdx.x * 256 + threadIdx.x;
    if (gid < nX8) { cast8(x, xb, gid * 8); return; }
    gid -= nX8;
    if (gid < nW8) { cast8(Wq, Wqkvb, gid * 8); return; }
    gid -= nW8;
    if (gid < nW8) { cast8(Wk, Wqkvb + D_DIM * D_DIM, gid * 8); return; }
    gid -= nW8;
    if (gid < nW8) { cast8(Wv, Wqkvb + 2 * D_DIM * D_DIM, gid * 8); return; }
    gid -= nW8;
    if (gid < nW8) { cast8(Wo, Wob, gid * 8); return; }
    gid -= nW8;
    if (gid < 384) { // 3072 bias elems, 8 per thread
        int i = gid * 8;
#pragma unroll
        for (int e = 0; e < 8; ++e) {
            int j = i + e;
            bqkv[j] = (j < 1024) ? bq[j] : (j < 2048 ? bk[j - 1024] : bv[j - 2048]);
        }
    }
}

__device__ __forceinline__ void storeC(float* p, float v) { *p = v; }
__device__ __forceinline__ void storeC(unsigned short* p, float v) { *p = f2b(v); }

enum { EPI_STORE = 0, EPI_QKV = 1, EPI_EXP = 2, EPI_INV = 3 };

// ---------- GEMM: C[M,N] = epi(scale*(A @ B^T) + bias), batched via blockIdx.z ----------
// m97 structure: 128x128 tile, 4 waves, 64x64/wave as 4x4 of 16x16x32 bf16 MFMA.
template <typename OutT, int EPI>
__global__ __launch_bounds__(256) void gemm_bt(
    const unsigned short* __restrict__ A, const unsigned short* __restrict__ B,
    OutT* __restrict__ C, const float* __restrict__ bias,
    int M, int N, int K, int lda, int ldb, int ldc,
    size_t sA, size_t sB, size_t sC, float scale,
    float* __restrict__ rs, unsigned short* __restrict__ vt) {
    __shared__ __align__(16) unsigned short As[128 * 32];
    __shared__ __align__(16) unsigned short Bs[128 * 32];

    A += (size_t)blockIdx.z * sA;
    B += (size_t)blockIdx.z * sB;
    C += (size_t)blockIdx.z * sC;

    const int tid  = threadIdx.x;
    const int wave = tid >> 6;
    const int lane = tid & 63;
    const int m0 = blockIdx.y * 128;
    const int n0 = blockIdx.x * 128;
    const int wm = (wave >> 1) * 64;
    const int wn = (wave & 1) * 64;
    const int lm = lane & 15;
    const int quad = lane >> 4;

    f32x4 acc[4][4];
#pragma unroll
    for (int i = 0; i < 4; ++i)
#pragma unroll
        for (int j = 0; j < 4; ++j)
#pragma unroll
            for (int e = 0; e < 4; ++e) acc[i][j][e] = 0.f;

    const int c0 = tid, c1 = tid + 256;
    const int r0 = c0 >> 2, kc0 = (c0 & 3) << 3;
    const int r1 = c1 >> 2, kc1 = (c1 & 3) << 3;
    const unsigned short* Ar0 = A + (size_t)(m0 + r0) * lda + kc0;
    const unsigned short* Ar1 = A + (size_t)(m0 + r1) * lda + kc1;
    const unsigned short* Br0 = B + (size_t)(n0 + r0) * ldb + kc0;
    const unsigned short* Br1 = B + (size_t)(n0 + r1) * ldb + kc1;

    for (int k0 = 0; k0 < K; k0 += 32) {
        gl_lds16(Ar0 + k0, &As[c0 * 8]);
        gl_lds16(Ar1 + k0, &As[c1 * 8]);
        gl_lds16(Br0 + k0, &Bs[c0 * 8]);
        gl_lds16(Br1 + k0, &Bs[c1 * 8]);
        __syncthreads();

        short8_t af[4], bf[4];
#pragma unroll
        for (int mi = 0; mi < 4; ++mi)
            af[mi] = *(const short8_t*)&As[(wm + mi * 16 + lm) * 32 + quad * 8];
#pragma unroll
        for (int ni = 0; ni < 4; ++ni)
            bf[ni] = *(const short8_t*)&Bs[(wn + ni * 16 + lm) * 32 + quad * 8];
#pragma unroll
        for (int mi = 0; mi < 4; ++mi)
#pragma unroll
            for (int ni = 0; ni < 4; ++ni)
                acc[mi][ni] = __builtin_amdgcn_mfma_f32_16x16x32_bf16(
                    af[mi], bf[ni], acc[mi][ni], 0, 0, 0);
        __syncthreads();
    }

    // C/D layout: col = lane&15 (+16*ni), row = quad*4 + e (+16*mi)
    if (EPI == EPI_STORE) {
#pragma unroll
        for (int ni = 0; ni < 4; ++ni) {
            const int col = n0 + wn + ni * 16 + lm;
            const float bv = bias ? bias[col] : 0.f;
#pragma unroll
            for (int mi = 0; mi < 4; ++mi)
#pragma unroll
                for (int e = 0; e < 4; ++e) {
                    const int row = m0 + wm + mi * 16 + quad * 4 + e;
                    storeC(&C[(size_t)row * ldc + col], acc[mi][ni][e] * scale + bv);
                }
        }
    } else if (EPI == EPI_QKV) {
        if (n0 < 2048) { // q,k -> C (ld 2048)
#pragma unroll
            for (int ni = 0; ni < 4; ++ni) {
                const int col = n0 + wn + ni * 16 + lm;
                const float bv = bias[col];
#pragma unroll
                for (int mi = 0; mi < 4; ++mi)
#pragma unroll
                    for (int e = 0; e < 4; ++e) {
                        const int row = m0 + wm + mi * 16 + quad * 4 + e;
                        storeC(&C[(size_t)row * ldc + col], acc[mi][ni][e] + bv);
                    }
            }
        } else { // v -> vt[b][d][s] transposed, 8B packed stores
#pragma unroll
            for (int ni = 0; ni < 4; ++ni) {
                const int col = n0 + wn + ni * 16 + lm;
                const int d = col - 2048;
                const float bv = bias[col];
#pragma unroll
                for (int mi = 0; mi < 4; ++mi) {
                    const int rr = m0 + wm + mi * 16 + quad * 4;
                    const int b = rr >> 12, s0 = rr & 4095;
                    ushort4 w;
                    w.x = f2b(acc[mi][ni][0] + bv);
                    w.y = f2b(acc[mi][ni][1] + bv);
                    w.z = f2b(acc[mi][ni][2] + bv);
                    w.w = f2b(acc[mi][ni][3] + bv);
                    *(ushort4*)&vt[((size_t)(b * D_DIM + d)) * S_LEN + s0] = w;
                }
            }
        }
    } else if (EPI == EPI_EXP) {
        float rp[4][4];
#pragma unroll
        for (int mi = 0; mi < 4; ++mi)
#pragma unroll
            for (int e = 0; e < 4; ++e) rp[mi][e] = 0.f;
#pragma unroll
        for (int ni = 0; ni < 4; ++ni) {
            const int col = n0 + wn + ni * 16 + lm;
#pragma unroll
            for (int mi = 0; mi < 4; ++mi)
#pragma unroll
                for (int e = 0; e < 4; ++e) {
                    const int row = m0 + wm + mi * 16 + quad * 4 + e;
                    const float p = __expf(acc[mi][ni][e] * scale);
                    storeC(&C[(size_t)row * ldc + col], p);
                    rp[mi][e] += p;
                }
        }
        // reduce across the 16 lm lanes (same quad)
#pragma unroll
        for (int off = 1; off <= 8; off <<= 1)
#pragma unroll
            for (int mi = 0; mi < 4; ++mi)
#pragma unroll
                for (int e = 0; e < 4; ++e)
                    rp[mi][e] += __shfl_xor(rp[mi][e], off);
        if (lm == 0) {
            float* rsz = rs + (size_t)blockIdx.z * M;
#pragma unroll
            for (int mi = 0; mi < 4; ++mi)
#pragma unroll
                for (int e = 0; e < 4; ++e)
                    atomicAdd(&rsz[m0 + wm + mi * 16 + quad * 4 + e], rp[mi][e]);
        }
    } else { // EPI_INV: scale rows by 1/rowSum
        const float* rsz = rs + (size_t)blockIdx.z * M;
        float inv[4][4];
#pragma unroll
        for (int mi = 0; mi < 4; ++mi) {
            float4 s4 = *(const float4*)&rsz[m0 + wm + mi * 16 + quad * 4];
            inv[mi][0] = 1.f / s4.x; inv[mi][1] = 1.f / s4.y;
            inv[mi][2] = 1.f / s4.z; inv[mi][3] = 1.f / s4.w;
        }
#pragma unroll
        for (int ni = 0; ni < 4; ++ni) {
            const int col = n0 + wn + ni * 16 + lm;
#pragma unroll
            for (int mi = 0; mi < 4; ++mi)
#pragma unroll
                for (int e = 0; e < 4; ++e) {
                    const int row = m0 + wm + mi * 16 + quad * 4 + e;
                    storeC(&C[(size_t)row * ldc + col], acc[mi][ni][e] * inv[mi][e]);
                }
        }
    }
}

// ---------- fallback-path kernels (round-2 equivalents) ----------
__global__ __launch_bounds__(256) void softmax_rows(unsigned short* __restrict__ P) {
    const int row = blockIdx.x;
    unsigned short* p = P + (size_t)row * S_LEN;
    const int t = threadIdx.x;
    short8_t r0 = ((const short8_t*)p)[2 * t];
    short8_t r1 = ((const short8_t*)p)[2 * t + 1];
    float v[16];
    float m = -1e30f;
#pragma unroll
    for (int i = 0; i < 8; ++i) { v[i] = b2f((unsigned short)r0[i]); m = fmaxf(m, v[i]); }
#pragma unroll
    for (int i = 0; i < 8; ++i) { v[8 + i] = b2f((unsigned short)r1[i]); m = fmaxf(m, v[8 + i]); }
#pragma unroll
    for (int off = 32; off >= 1; off >>= 1) m = fmaxf(m, __shfl_xor(m, off));
    __shared__ float redm[4];
    if ((t & 63) == 0) redm[t >> 6] = m;
    __syncthreads();
    m = fmaxf(fmaxf(redm[0], redm[1]), fmaxf(redm[2], redm[3]));
    float s = 0.f;
#pragma unroll
    for (int i = 0; i < 16; ++i) { v[i] = __expf(v[i] - m); s += v[i]; }
#pragma unroll
    for (int off = 32; off >= 1; off >>= 1) s += __shfl_xor(s, off);
    __shared__ float reds[4];
    if ((t & 63) == 0) reds[t >> 6] = s;
    __syncthreads();
    s = reds[0] + reds[1] + reds[2] + reds[3];
    const float inv = 1.f / s;
    short8_t w0, w1;
#pragma unroll
    for (int i = 0; i < 8; ++i) w0[i] = (short)f2b(v[i] * inv);
#pragma unroll
    for (int i = 0; i < 8; ++i) w1[i] = (short)f2b(v[8 + i] * inv);
    ((short8_t*)p)[2 * t] = w0;
    ((short8_t*)p)[2 * t + 1] = w1;
}

__global__ __launch_bounds__(256) void transpose_sd(
    const unsigned short* __restrict__ src, int srcLd, size_t sSrc,
    unsigned short* __restrict__ dst, size_t sDst) {
    __shared__ unsigned short tile[32][33];
    src += (size_t)blockIdx.z * sSrc;
    dst += (size_t)blockIdx.z * sDst;
    const int d = blockIdx.x * 32 + threadIdx.x;
    const int s = blockIdx.y * 32 + threadIdx.y;
#pragma unroll
    for (int j = 0; j < 32; j += 8)
        tile[threadIdx.y + j][threadIdx.x] = src[(size_t)(s + j) * srcLd + d];
    __syncthreads();
    const int d2 = blockIdx.x * 32 + threadIdx.y;
    const int s2 = blockIdx.y * 32 + threadIdx.x;
#pragma unroll
    for (int j = 0; j < 32; j += 8)
        dst[(size_t)(d2 + j) * S_LEN + s2] = tile[threadIdx.x][threadIdx.y + j];
}

extern "C" void kernel_launch(void* const* d_in, const int* in_sizes, int n_in,
                              void* d_out, int out_size, void* d_ws, size_t ws_size,
                              hipStream_t stream) {
    const float* x  = (const float*)d_in[0];
    const float* Wq = (const float*)d_in[1];
    const float* bq = (const float*)d_in[2];
    const float* Wk = (const float*)d_in[3];
    const float* bk = (const float*)d_in[4];
    const float* Wv = (const float*)d_in[5];
    const float* bv = (const float*)d_in[6];
    const float* Wo = (const float*)d_in[7];
    const float* bo = (const float*)d_in[8];
    float* out = (float*)d_out;

    char* ws = (char*)d_ws;
    const size_t MB = 1ull << 20;
    const size_t KB = 1ull << 10;
    const int nX = BATCH * S_LEN * D_DIM;
    const int nW = D_DIM * D_DIM;
    const int SR = BATCH * S_LEN;
    const int prepBlocks = (nX / 8 + 4 * (nW / 8) + 384 + 255) / 256;

    int nb = 0;
    if (ws_size >= 169 * MB + 32 * MB)
        nb = (int)((ws_size - 169 * MB) / (32 * MB));
    if (nb > BATCH) nb = BATCH;

    if (nb >= 1) {
        // layout: qkb[0,64) vtb[64,96) Wqkvb[96,102) Wob[102,104)
        //         bqkv@104MB rowSums@104MB+64KB xb[105,137) ctx[137,169) P[169,..)
        unsigned short* qkb   = (unsigned short*)(ws + 0);
        unsigned short* vtb   = (unsigned short*)(ws + 64 * MB);
        unsigned short* Wqkvb = (unsigned short*)(ws + 96 * MB);
        unsigned short* Wob   = (unsigned short*)(ws + 102 * MB);
        float*          bqkv  = (float*)(ws + 104 * MB);
        float*          rowS  = (float*)(ws + 104 * MB + 64 * KB);
        unsigned short* xb    = (unsigned short*)(ws + 105 * MB);
        unsigned short* ctx   = (unsigned short*)(ws + 137 * MB);
        unsigned short* Pb    = (unsigned short*)(ws + 169 * MB);

        hipMemsetAsync(rowS, 0, (size_t)SR * sizeof(float), stream);
        prep<<<prepBlocks, 256, 0, stream>>>(x, Wq, Wk, Wv, Wo, bq, bk, bv,
                                             xb, Wqkvb, Wob, bqkv);

        // QKV: q,k -> qkb (ld 2048), v -> vtb transposed
        gemm_bt<unsigned short, EPI_QKV><<<dim3(3072 / 128, SR / 128, 1), 256, 0, stream>>>(
            xb, Wqkvb, qkb, bqkv, SR, 3072, D_DIM,
            D_DIM, D_DIM, 2048, 0, 0, 0, 1.f, nullptr, vtb);

        const unsigned short* qp = qkb;
        const unsigned short* kp = qkb + 1024;
        for (int b0 = 0; b0 < BATCH; b0 += nb) {
            int g = (BATCH - b0 < nb) ? (BATCH - b0) : nb;
            const size_t qoff = (size_t)b0 * S_LEN * 2048;
            // scores: P = exp(scale * q@k^T), rowSums += row partials
            gemm_bt<unsigned short, EPI_EXP><<<dim3(S_LEN / 128, S_LEN / 128, g), 256, 0, stream>>>(
                qp + qoff, kp + qoff, Pb, nullptr, S_LEN, S_LEN, D_DIM,
                2048, 2048, S_LEN,
                (size_t)S_LEN * 2048, (size_t)S_LEN * 2048, (size_t)S_LEN * S_LEN,
                ATTN_SCALE, rowS + (size_t)b0 * S_LEN, nullptr);
            // context: ctx = (P @ (V^T)^T) / rowSum
            gemm_bt<unsigned short, EPI_INV><<<dim3(D_DIM / 128, S_LEN / 128, g), 256, 0, stream>>>(
                Pb, vtb + (size_t)b0 * D_DIM * S_LEN,
                ctx + (size_t)b0 * S_LEN * D_DIM, nullptr,
                S_LEN, D_DIM, S_LEN,
                S_LEN, S_LEN, D_DIM,
                (size_t)S_LEN * S_LEN, (size_t)D_DIM * S_LEN, (size_t)S_LEN * D_DIM,
                1.f, rowS + (size_t)b0 * S_LEN, nullptr);
        }

        // out = ctx @ Wo^T + bo
        gemm_bt<float, EPI_STORE><<<dim3(D_DIM / 128, SR / 128, 1), 256, 0, stream>>>(
            ctx, Wob, out, bo, SR, D_DIM, D_DIM,
            D_DIM, D_DIM, D_DIM, 0, 0, 0, 1.f, nullptr, nullptr);
    } else {
        // -------- fallback (ws too small): round-2 equivalent --------
        unsigned short* xb    = (unsigned short*)(ws + 0);
        unsigned short* Pb    = (unsigned short*)(ws + 0); // alias
        unsigned short* Wqkvb = (unsigned short*)(ws + 32 * MB);
        unsigned short* Wob   = (unsigned short*)(ws + 38 * MB);
        float*          bqkv  = (float*)(ws + 40 * MB);
        unsigned short* qb    = (unsigned short*)(ws + 41 * MB);
        unsigned short* kb    = (unsigned short*)(ws + 73 * MB);
        unsigned short* vb    = (unsigned short*)(ws + 105 * MB);
        unsigned short* vtb   = (unsigned short*)(ws + 137 * MB);
        unsigned short* ctx   = (unsigned short*)(ws + 169 * MB);

        prep<<<prepBlocks, 256, 0, stream>>>(x, Wq, Wk, Wv, Wo, bq, bk, bv,
                                             xb, Wqkvb, Wob, bqkv);

        dim3 gproj(D_DIM / 128, SR / 128, 1);
        gemm_bt<unsigned short, EPI_STORE><<<gproj, 256, 0, stream>>>(xb, Wqkvb, qb, bq,
            SR, D_DIM, D_DIM, D_DIM, D_DIM, D_DIM, 0, 0, 0, 1.f, nullptr, nullptr);
        gemm_bt<unsigned short, EPI_STORE><<<gproj, 256, 0, stream>>>(xb, Wqkvb + nW, kb, bk,
            SR, D_DIM, D_DIM, D_DIM, D_DIM, D_DIM, 0, 0, 0, 1.f, nullptr, nullptr);
        gemm_bt<unsigned short, EPI_STORE><<<gproj, 256, 0, stream>>>(xb, Wqkvb + 2 * nW, vb, bv,
            SR, D_DIM, D_DIM, D_DIM, D_DIM, D_DIM, 0, 0, 0, 1.f, nullptr, nullptr);

        transpose_sd<<<dim3(D_DIM / 32, S_LEN / 32, BATCH), dim3(32, 8), 0, stream>>>(
            vb, D_DIM, (size_t)S_LEN * D_DIM, vtb, (size_t)D_DIM * S_LEN);

        for (int b = 0; b < BATCH; ++b) {
            const size_t sd = (size_t)b * S_LEN * D_DIM;
            const size_t ds = (size_t)b * D_DIM * S_LEN;
            gemm_bt<unsigned short, EPI_STORE><<<dim3(S_LEN / 128, S_LEN / 128, 1), 256, 0, stream>>>(
                qb + sd, kb + sd, Pb, nullptr, S_LEN, S_LEN, D_DIM,
                D_DIM, D_DIM, S_LEN, 0, 0, 0, ATTN_SCALE, nullptr, nullptr);
            softmax_rows<<<S_LEN, 256, 0, stream>>>(Pb);
            gemm_bt<unsigned short, EPI_STORE><<<dim3(D_DIM / 128, S_LEN / 128, 1), 256, 0, stream>>>(
                Pb, vtb + ds, ctx, nullptr, S_LEN, D_DIM, S_LEN,
                S_LEN, S_LEN, D_DIM, 0, 0, 0, 1.f, nullptr, nullptr);
            gemm_bt<float, EPI_STORE><<<dim3(D_DIM / 128, S_LEN / 128, 1), 256, 0, stream>>>(
                ctx, Wob, out + sd, bo, S_LEN, D_DIM, D_DIM,
                D_DIM, D_DIM, D_DIM, 0, 0, 0, 1.f, nullptr, nullptr);
        }
    }
}

// Round 4
// 778.444 us; speedup vs baseline: 1.0645x; 1.0645x over previous
//
#include <hip/hip_runtime.h>
#include <stdint.h>

#define BATCH 4
#define S_LEN 4096
#define D_DIM 1024
static constexpr float ATTN_SCALE = 0.03125f; // 1/sqrt(1024)

typedef __attribute__((ext_vector_type(8))) short short8_t;
typedef __attribute__((ext_vector_type(4))) float f32x4;

// ---------- bf16 helpers ----------
__device__ __forceinline__ unsigned short f2b(float f) {
    union { float f; uint32_t i; } x; x.f = f;
    uint32_t r = x.i + 0x7FFF + ((x.i >> 16) & 1);
    return (unsigned short)(r >> 16);
}
__device__ __forceinline__ float b2f(unsigned short u) {
    union { uint32_t i; float f; } x; x.i = ((uint32_t)u) << 16;
    return x.f;
}

// ---------- async global->LDS 16B ----------
__device__ __forceinline__ void gl_lds16(const unsigned short* g, unsigned short* l) {
    __builtin_amdgcn_global_load_lds(
        (const __attribute__((address_space(1))) uint32_t*)(const void*)g,
        (__attribute__((address_space(3))) uint32_t*)(void*)l,
        16, 0, 0);
}

// ---------- one prep kernel: all casts + bias pack ----------
__device__ __forceinline__ void cast8(const float* in, unsigned short* out, int i) {
    float4 a = *(const float4*)(in + i);
    float4 b = *(const float4*)(in + i + 4);
    short8_t o;
    o[0] = (short)f2b(a.x); o[1] = (short)f2b(a.y);
    o[2] = (short)f2b(a.z); o[3] = (short)f2b(a.w);
    o[4] = (short)f2b(b.x); o[5] = (short)f2b(b.y);
    o[6] = (short)f2b(b.z); o[7] = (short)f2b(b.w);
    *(short8_t*)(out + i) = o;
}

__global__ __launch_bounds__(256) void prep(
    const float* __restrict__ x,
    const float* __restrict__ Wq, const float* __restrict__ Wk,
    const float* __restrict__ Wv, const float* __restrict__ Wo,
    const float* __restrict__ bq, const float* __restrict__ bk,
    const float* __restrict__ bv,
    unsigned short* __restrict__ xb, unsigned short* __restrict__ Wqkvb,
    unsigned short* __restrict__ Wob, float* __restrict__ bqkv) {
    const int nX8 = (BATCH * S_LEN * D_DIM) / 8;
    const int nW8 = (D_DIM * D_DIM) / 8;
    int gid = blockIdx.x * 256 + threadIdx.x;
    if (gid < nX8) { cast8(x, xb, gid * 8); return; }
    gid -= nX8;
    if (gid < nW8) { cast8(Wq, Wqkvb, gid * 8); return; }
    gid -= nW8;
    if (gid < nW8) { cast8(Wk, Wqkvb + D_DIM * D_DIM, gid * 8); return; }
    gid -= nW8;
    if (gid < nW8) { cast8(Wv, Wqkvb + 2 * D_DIM * D_DIM, gid * 8); return; }
    gid -= nW8;
    if (gid < nW8) { cast8(Wo, Wob, gid * 8); return; }
    gid -= nW8;
    if (gid < 384) {
        int i = gid * 8;
#pragma unroll
        for (int e = 0; e < 8; ++e) {
            int j = i + e;
            bqkv[j] = (j < 1024) ? bq[j] : (j < 2048 ? bk[j - 1024] : bv[j - 2048]);
        }
    }
}

__device__ __forceinline__ void storeC(float* p, float v) { *p = v; }
__device__ __forceinline__ void storeC(unsigned short* p, float v) { *p = f2b(v); }

enum { EPI_STORE = 0, EPI_QKV = 1, EPI_EXP = 2, EPI_INV = 3 };

// ---------- GEMM core: C[M,N] = epi(scale*(A @ B^T) + bias) ----------
// Grid: blockIdx.x = M-tile, blockIdx.y = N-tile (M-major for XCD L2 locality),
// blockIdx.z = batch. m97 structure: 128x128 tile, 4 waves, 4x4 of 16x16x32 MFMA.
template <typename OutT, int EPI>
__device__ __forceinline__ void gemm_core(
    const unsigned short* __restrict__ A, const unsigned short* __restrict__ B,
    OutT* __restrict__ C, const float* __restrict__ bias,
    int M, int N, int K, int lda, int ldb, int ldc,
    size_t sA, size_t sB, size_t sC, float scale,
    float* __restrict__ rs, unsigned short* __restrict__ vt) {
    __shared__ __align__(16) unsigned short As[128 * 32];
    __shared__ __align__(16) unsigned short Bs[128 * 32];

    A += (size_t)blockIdx.z * sA;
    B += (size_t)blockIdx.z * sB;
    C += (size_t)blockIdx.z * sC;

    const int tid  = threadIdx.x;
    const int wave = tid >> 6;
    const int lane = tid & 63;
    const int m0 = blockIdx.x * 128;   // grid transposed: x = M-tile
    const int n0 = blockIdx.y * 128;
    const int wm = (wave >> 1) * 64;
    const int wn = (wave & 1) * 64;
    const int lm = lane & 15;
    const int quad = lane >> 4;

    f32x4 acc[4][4];
#pragma unroll
    for (int i = 0; i < 4; ++i)
#pragma unroll
        for (int j = 0; j < 4; ++j)
#pragma unroll
            for (int e = 0; e < 4; ++e) acc[i][j][e] = 0.f;

    const int c0 = tid, c1 = tid + 256;
    const int r0 = c0 >> 2, kc0 = (c0 & 3) << 3;
    const int r1 = c1 >> 2, kc1 = (c1 & 3) << 3;
    const unsigned short* Ar0 = A + (size_t)(m0 + r0) * lda + kc0;
    const unsigned short* Ar1 = A + (size_t)(m0 + r1) * lda + kc1;
    const unsigned short* Br0 = B + (size_t)(n0 + r0) * ldb + kc0;
    const unsigned short* Br1 = B + (size_t)(n0 + r1) * ldb + kc1;

    for (int k0 = 0; k0 < K; k0 += 32) {
        gl_lds16(Ar0 + k0, &As[c0 * 8]);
        gl_lds16(Ar1 + k0, &As[c1 * 8]);
        gl_lds16(Br0 + k0, &Bs[c0 * 8]);
        gl_lds16(Br1 + k0, &Bs[c1 * 8]);
        __syncthreads();

        short8_t af[4], bf[4];
#pragma unroll
        for (int mi = 0; mi < 4; ++mi)
            af[mi] = *(const short8_t*)&As[(wm + mi * 16 + lm) * 32 + quad * 8];
#pragma unroll
        for (int ni = 0; ni < 4; ++ni)
            bf[ni] = *(const short8_t*)&Bs[(wn + ni * 16 + lm) * 32 + quad * 8];
#pragma unroll
        for (int mi = 0; mi < 4; ++mi)
#pragma unroll
            for (int ni = 0; ni < 4; ++ni)
                acc[mi][ni] = __builtin_amdgcn_mfma_f32_16x16x32_bf16(
                    af[mi], bf[ni], acc[mi][ni], 0, 0, 0);
        __syncthreads();
    }

    // C/D layout: col = lane&15 (+16*ni), row = quad*4 + e (+16*mi)
    if constexpr (EPI == EPI_STORE) {
#pragma unroll
        for (int ni = 0; ni < 4; ++ni) {
            const int col = n0 + wn + ni * 16 + lm;
            const float bv = bias ? bias[col] : 0.f;
#pragma unroll
            for (int mi = 0; mi < 4; ++mi)
#pragma unroll
                for (int e = 0; e < 4; ++e) {
                    const int row = m0 + wm + mi * 16 + quad * 4 + e;
                    storeC(&C[(size_t)row * ldc + col], acc[mi][ni][e] * scale + bv);
                }
        }
    } else if constexpr (EPI == EPI_QKV) {
        if (n0 < 2048) { // q,k -> C (ld 2048)
#pragma unroll
            for (int ni = 0; ni < 4; ++ni) {
                const int col = n0 + wn + ni * 16 + lm;
                const float bv = bias[col];
#pragma unroll
                for (int mi = 0; mi < 4; ++mi)
#pragma unroll
                    for (int e = 0; e < 4; ++e) {
                        const int row = m0 + wm + mi * 16 + quad * 4 + e;
                        storeC(&C[(size_t)row * ldc + col], acc[mi][ni][e] + bv);
                    }
            }
        } else {
            // v -> vt[b][d][s]: transpose 64x64 wave subtile through padded LDS,
            // then 16B/lane coalesced stores (128B contiguous per d-row).
            __shared__ __align__(16) uint32_t xl[4][64 * 33];
            uint32_t* xw = xl[wave];
#pragma unroll
            for (int ni = 0; ni < 4; ++ni) {
                const int dl = ni * 16 + lm;
                const float bv = bias[n0 + wn + dl];
#pragma unroll
                for (int mi = 0; mi < 4; ++mi) {
                    const int sw = (mi * 16 + quad * 4) >> 1; // word index
                    uint32_t p0 = (uint32_t)f2b(acc[mi][ni][0] + bv) |
                                  ((uint32_t)f2b(acc[mi][ni][1] + bv) << 16);
                    uint32_t p1 = (uint32_t)f2b(acc[mi][ni][2] + bv) |
                                  ((uint32_t)f2b(acc[mi][ni][3] + bv) << 16);
                    xw[dl * 33 + sw]     = p0;
                    xw[dl * 33 + sw + 1] = p1;
                }
            }
            __syncthreads(); // block-uniform branch (n0 is block-uniform)
            const int rowg = m0 + wm;
            const int b = rowg >> 12;
            const int sbase = rowg & 4095;
            const int d0 = (n0 - 2048) + wn;
            const int lr = lane >> 3; // 0..7
            const int lc = lane & 7;  // 0..7
#pragma unroll
            for (int rr = 0; rr < 8; ++rr) {
                const int dl = rr * 8 + lr;
                uint4 w;
                w.x = xw[dl * 33 + lc * 4 + 0];
                w.y = xw[dl * 33 + lc * 4 + 1];
                w.z = xw[dl * 33 + lc * 4 + 2];
                w.w = xw[dl * 33 + lc * 4 + 3];
                *(uint4*)&vt[((size_t)(b * D_DIM + d0 + dl)) * S_LEN + sbase + lc * 8] = w;
            }
        }
    } else if constexpr (EPI == EPI_EXP) {
        float rp[4][4];
#pragma unroll
        for (int mi = 0; mi < 4; ++mi)
#pragma unroll
            for (int e = 0; e < 4; ++e) rp[mi][e] = 0.f;
#pragma unroll
        for (int ni = 0; ni < 4; ++ni) {
            const int col = n0 + wn + ni * 16 + lm;
#pragma unroll
            for (int mi = 0; mi < 4; ++mi)
#pragma unroll
                for (int e = 0; e < 4; ++e) {
                    const int row = m0 + wm + mi * 16 + quad * 4 + e;
                    const float p = __expf(acc[mi][ni][e] * scale);
                    storeC(&C[(size_t)row * ldc + col], p);
                    rp[mi][e] += p;
                }
        }
#pragma unroll
        for (int off = 1; off <= 8; off <<= 1)
#pragma unroll
            for (int mi = 0; mi < 4; ++mi)
#pragma unroll
                for (int e = 0; e < 4; ++e)
                    rp[mi][e] += __shfl_xor(rp[mi][e], off);
        if (lm == 0) {
            float* rsz = rs + (size_t)blockIdx.z * M;
#pragma unroll
            for (int mi = 0; mi < 4; ++mi)
#pragma unroll
                for (int e = 0; e < 4; ++e)
                    atomicAdd(&rsz[m0 + wm + mi * 16 + quad * 4 + e], rp[mi][e]);
        }
    } else { // EPI_INV
        const float* rsz = rs + (size_t)blockIdx.z * M;
        float inv[4][4];
#pragma unroll
        for (int mi = 0; mi < 4; ++mi) {
            float4 s4 = *(const float4*)&rsz[m0 + wm + mi * 16 + quad * 4];
            inv[mi][0] = 1.f / s4.x; inv[mi][1] = 1.f / s4.y;
            inv[mi][2] = 1.f / s4.z; inv[mi][3] = 1.f / s4.w;
        }
#pragma unroll
        for (int ni = 0; ni < 4; ++ni) {
            const int col = n0 + wn + ni * 16 + lm;
#pragma unroll
            for (int mi = 0; mi < 4; ++mi)
#pragma unroll
                for (int e = 0; e < 4; ++e) {
                    const int row = m0 + wm + mi * 16 + quad * 4 + e;
                    storeC(&C[(size_t)row * ldc + col], acc[mi][ni][e] * inv[mi][e]);
                }
        }
    }
}

// ---------- named phase kernels (profiler visibility) ----------
#define GEMM_ARGS const unsigned short* A, const unsigned short* B, void* C, \
    const float* bias, int M, int N, int K, int lda, int ldb, int ldc, \
    size_t sA, size_t sB, size_t sC, float scale, float* rs, unsigned short* vt

__global__ __launch_bounds__(256) void qkv_gemm(GEMM_ARGS) {
    gemm_core<unsigned short, EPI_QKV>(A, B, (unsigned short*)C, bias, M, N, K,
        lda, ldb, ldc, sA, sB, sC, scale, rs, vt);
}
__global__ __launch_bounds__(256) void scores_gemm(GEMM_ARGS) {
    gemm_core<unsigned short, EPI_EXP>(A, B, (unsigned short*)C, bias, M, N, K,
        lda, ldb, ldc, sA, sB, sC, scale, rs, vt);
}
__global__ __launch_bounds__(256) void ctx_gemm(GEMM_ARGS) {
    gemm_core<unsigned short, EPI_INV>(A, B, (unsigned short*)C, bias, M, N, K,
        lda, ldb, ldc, sA, sB, sC, scale, rs, vt);
}
__global__ __launch_bounds__(256) void out_gemm(GEMM_ARGS) {
    gemm_core<float, EPI_STORE>(A, B, (float*)C, bias, M, N, K,
        lda, ldb, ldc, sA, sB, sC, scale, rs, vt);
}
__global__ __launch_bounds__(256) void plain_gemm_bf16(GEMM_ARGS) {
    gemm_core<unsigned short, EPI_STORE>(A, B, (unsigned short*)C, bias, M, N, K,
        lda, ldb, ldc, sA, sB, sC, scale, rs, vt);
}

// ---------- fallback-path kernels ----------
__global__ __launch_bounds__(256) void softmax_rows(unsigned short* __restrict__ P) {
    const int row = blockIdx.x;
    unsigned short* p = P + (size_t)row * S_LEN;
    const int t = threadIdx.x;
    short8_t r0 = ((const short8_t*)p)[2 * t];
    short8_t r1 = ((const short8_t*)p)[2 * t + 1];
    float v[16];
    float m = -1e30f;
#pragma unroll
    for (int i = 0; i < 8; ++i) { v[i] = b2f((unsigned short)r0[i]); m = fmaxf(m, v[i]); }
#pragma unroll
    for (int i = 0; i < 8; ++i) { v[8 + i] = b2f((unsigned short)r1[i]); m = fmaxf(m, v[8 + i]); }
#pragma unroll
    for (int off = 32; off >= 1; off >>= 1) m = fmaxf(m, __shfl_xor(m, off));
    __shared__ float redm[4];
    if ((t & 63) == 0) redm[t >> 6] = m;
    __syncthreads();
    m = fmaxf(fmaxf(redm[0], redm[1]), fmaxf(redm[2], redm[3]));
    float s = 0.f;
#pragma unroll
    for (int i = 0; i < 16; ++i) { v[i] = __expf(v[i] - m); s += v[i]; }
#pragma unroll
    for (int off = 32; off >= 1; off >>= 1) s += __shfl_xor(s, off);
    __shared__ float reds[4];
    if ((t & 63) == 0) reds[t >> 6] = s;
    __syncthreads();
    s = reds[0] + reds[1] + reds[2] + reds[3];
    const float inv = 1.f / s;
    short8_t w0, w1;
#pragma unroll
    for (int i = 0; i < 8; ++i) w0[i] = (short)f2b(v[i] * inv);
#pragma unroll
    for (int i = 0; i < 8; ++i) w1[i] = (short)f2b(v[8 + i] * inv);
    ((short8_t*)p)[2 * t] = w0;
    ((short8_t*)p)[2 * t + 1] = w1;
}

__global__ __launch_bounds__(256) void transpose_sd(
    const unsigned short* __restrict__ src, int srcLd, size_t sSrc,
    unsigned short* __restrict__ dst, size_t sDst) {
    __shared__ unsigned short tile[32][33];
    src += (size_t)blockIdx.z * sSrc;
    dst += (size_t)blockIdx.z * sDst;
    const int d = blockIdx.x * 32 + threadIdx.x;
    const int s = blockIdx.y * 32 + threadIdx.y;
#pragma unroll
    for (int j = 0; j < 32; j += 8)
        tile[threadIdx.y + j][threadIdx.x] = src[(size_t)(s + j) * srcLd + d];
    __syncthreads();
    const int d2 = blockIdx.x * 32 + threadIdx.y;
    const int s2 = blockIdx.y * 32 + threadIdx.x;
#pragma unroll
    for (int j = 0; j < 32; j += 8)
        dst[(size_t)(d2 + j) * S_LEN + s2] = tile[threadIdx.x][threadIdx.y + j];
}

extern "C" void kernel_launch(void* const* d_in, const int* in_sizes, int n_in,
                              void* d_out, int out_size, void* d_ws, size_t ws_size,
                              hipStream_t stream) {
    const float* x  = (const float*)d_in[0];
    const float* Wq = (const float*)d_in[1];
    const float* bq = (const float*)d_in[2];
    const float* Wk = (const float*)d_in[3];
    const float* bk = (const float*)d_in[4];
    const float* Wv = (const float*)d_in[5];
    const float* bv = (const float*)d_in[6];
    const float* Wo = (const float*)d_in[7];
    const float* bo = (const float*)d_in[8];
    float* out = (float*)d_out;

    char* ws = (char*)d_ws;
    const size_t MB = 1ull << 20;
    const size_t KB = 1ull << 10;
    const int nX = BATCH * S_LEN * D_DIM;
    const int nW = D_DIM * D_DIM;
    const int SR = BATCH * S_LEN;
    const int prepBlocks = (nX / 8 + 4 * (nW / 8) + 384 + 255) / 256;

    int nb = 0;
    if (ws_size >= 169 * MB + 32 * MB)
        nb = (int)((ws_size - 169 * MB) / (32 * MB));
    if (nb > BATCH) nb = BATCH;

    if (nb >= 1) {
        unsigned short* qkb   = (unsigned short*)(ws + 0);        // 64 MB q,k ld2048
        unsigned short* vtb   = (unsigned short*)(ws + 64 * MB);  // 32 MB V^T
        unsigned short* Wqkvb = (unsigned short*)(ws + 96 * MB);
        unsigned short* Wob   = (unsigned short*)(ws + 102 * MB);
        float*          bqkv  = (float*)(ws + 104 * MB);
        float*          rowS  = (float*)(ws + 104 * MB + 64 * KB);
        unsigned short* xb    = (unsigned short*)(ws + 105 * MB);
        unsigned short* ctx   = (unsigned short*)(ws + 137 * MB);
        unsigned short* Pb    = (unsigned short*)(ws + 169 * MB);

        hipMemsetAsync(rowS, 0, (size_t)SR * sizeof(float), stream);
        prep<<<prepBlocks, 256, 0, stream>>>(x, Wq, Wk, Wv, Wo, bq, bk, bv,
                                             xb, Wqkvb, Wob, bqkv);

        // QKV: q,k -> qkb (ld 2048), v -> vtb transposed. grid (M,N) M-major.
        qkv_gemm<<<dim3(SR / 128, 3072 / 128, 1), 256, 0, stream>>>(
            xb, Wqkvb, qkb, bqkv, SR, 3072, D_DIM,
            D_DIM, D_DIM, 2048, 0, 0, 0, 1.f, nullptr, vtb);

        const unsigned short* qp = qkb;
        const unsigned short* kp = qkb + 1024;
        for (int b0 = 0; b0 < BATCH; b0 += nb) {
            int g = (BATCH - b0 < nb) ? (BATCH - b0) : nb;
            const size_t qoff = (size_t)b0 * S_LEN * 2048;
            scores_gemm<<<dim3(S_LEN / 128, S_LEN / 128, g), 256, 0, stream>>>(
                qp + qoff, kp + qoff, Pb, nullptr, S_LEN, S_LEN, D_DIM,
                2048, 2048, S_LEN,
                (size_t)S_LEN * 2048, (size_t)S_LEN * 2048, (size_t)S_LEN * S_LEN,
                ATTN_SCALE, rowS + (size_t)b0 * S_LEN, nullptr);
            ctx_gemm<<<dim3(S_LEN / 128, D_DIM / 128, g), 256, 0, stream>>>(
                Pb, vtb + (size_t)b0 * D_DIM * S_LEN,
                ctx + (size_t)b0 * S_LEN * D_DIM, nullptr,
                S_LEN, D_DIM, S_LEN,
                S_LEN, S_LEN, D_DIM,
                (size_t)S_LEN * S_LEN, (size_t)D_DIM * S_LEN, (size_t)S_LEN * D_DIM,
                1.f, rowS + (size_t)b0 * S_LEN, nullptr);
        }

        out_gemm<<<dim3(SR / 128, D_DIM / 128, 1), 256, 0, stream>>>(
            ctx, Wob, out, bo, SR, D_DIM, D_DIM,
            D_DIM, D_DIM, D_DIM, 0, 0, 0, 1.f, nullptr, nullptr);
    } else {
        // -------- fallback (ws too small) --------
        unsigned short* xb    = (unsigned short*)(ws + 0);
        unsigned short* Pb    = (unsigned short*)(ws + 0); // alias
        unsigned short* Wqkvb = (unsigned short*)(ws + 32 * MB);
        unsigned short* Wob   = (unsigned short*)(ws + 38 * MB);
        float*          bqkv  = (float*)(ws + 40 * MB);
        unsigned short* qb    = (unsigned short*)(ws + 41 * MB);
        unsigned short* kb    = (unsigned short*)(ws + 73 * MB);
        unsigned short* vb    = (unsigned short*)(ws + 105 * MB);
        unsigned short* vtb   = (unsigned short*)(ws + 137 * MB);
        unsigned short* ctx   = (unsigned short*)(ws + 169 * MB);

        prep<<<prepBlocks, 256, 0, stream>>>(x, Wq, Wk, Wv, Wo, bq, bk, bv,
                                             xb, Wqkvb, Wob, bqkv);

        dim3 gproj(SR / 128, D_DIM / 128, 1);
        plain_gemm_bf16<<<gproj, 256, 0, stream>>>(xb, Wqkvb, qb, bq,
            SR, D_DIM, D_DIM, D_DIM, D_DIM, D_DIM, 0, 0, 0, 1.f, nullptr, nullptr);
        plain_gemm_bf16<<<gproj, 256, 0, stream>>>(xb, Wqkvb + nW, kb, bk,
            SR, D_DIM, D_DIM, D_DIM, D_DIM, D_DIM, 0, 0, 0, 1.f, nullptr, nullptr);
        plain_gemm_bf16<<<gproj, 256, 0, stream>>>(xb, Wqkvb + 2 * nW, vb, bv,
            SR, D_DIM, D_DIM, D_DIM, D_DIM, D_DIM, 0, 0, 0, 1.f, nullptr, nullptr);

        transpose_sd<<<dim3(D_DIM / 32, S_LEN / 32, BATCH), dim3(32, 8), 0, stream>>>(
            vb, D_DIM, (size_t)S_LEN * D_DIM, vtb, (size_t)D_DIM * S_LEN);

        for (int b = 0; b < BATCH; ++b) {
            const size_t sd = (size_t)b * S_LEN * D_DIM;
            const size_t ds = (size_t)b * D_DIM * S_LEN;
            plain_gemm_bf16<<<dim3(S_LEN / 128, S_LEN / 128, 1), 256, 0, stream>>>(
                qb + sd, kb + sd, Pb, nullptr, S_LEN, S_LEN, D_DIM,
                D_DIM, D_DIM, S_LEN, 0, 0, 0, ATTN_SCALE, nullptr, nullptr);
            softmax_rows<<<S_LEN, 256, 0, stream>>>(Pb);
            plain_gemm_bf16<<<dim3(S_LEN / 128, D_DIM / 128, 1), 256, 0, stream>>>(
                Pb, vtb + ds, ctx, nullptr, S_LEN, D_DIM, S_LEN,
                S_LEN, S_LEN, D_DIM, 0, 0, 0, 1.f, nullptr, nullptr);
            out_gemm<<<dim3(S_LEN / 128, D_DIM / 128, 1), 256, 0, stream>>>(
                ctx, Wob, out + sd, bo, S_LEN, D_DIM, D_DIM,
                D_DIM, D_DIM, D_DIM, 0, 0, 0, 1.f, nullptr, nullptr);
        }
    }
}